// Round 4
// baseline (1219.944 us; speedup 1.0000x reference)
//
#include <hip/hip_runtime.h>
#include <hip/hip_bf16.h>
#include <stdint.h>

typedef __hip_bfloat16 bf16;

__device__ __forceinline__ float b2f(bf16 x) { return __bfloat162float(x); }
__device__ __forceinline__ float bits2f(uint32_t u) {
    union { uint32_t i; float f; } c; c.i = u; return c.f;
}

// ---------------------------------------------------------------------------
// Mode detection: 0 = bf16 external tensors, 1 = f32.
// ---------------------------------------------------------------------------
__global__ void detect_mode_kernel(const uint16_t* __restrict__ nf, int* __restrict__ flag) {
    if (threadIdx.x != 0 || blockIdx.x != 0) return;
    int sane = 0;
    for (int i = 0; i < 256; ++i) {
        uint32_t u = nf[2 * i];
        float a = fabsf(bits2f(u << 16));
        if (a == 0.f || (a > 1e-5f && a < 100.f)) ++sane;
    }
    flag[0] = (sane >= 128) ? 0 : 1;
}

struct ParamTable {
    const void* src[14];
    int off[15];
};

__global__ void convert_params_kernel(ParamTable T, const int* __restrict__ mode,
                                      float* __restrict__ out) {
    int i = blockIdx.x * blockDim.x + threadIdx.x;
    if (i >= T.off[14]) return;
    int k = 0;
    while (k < 13 && i >= T.off[k + 1]) ++k;
    int j = i - T.off[k];
    out[i] = (*mode == 0) ? b2f(((const bf16*)T.src[k])[j]) : ((const float*)T.src[k])[j];
}

// wae[d*3+h] = sum_f We[d*96 + h*32 + f] * ae[h*32 + f]
__global__ void fold_wae_kernel(const float* __restrict__ We, const float* __restrict__ ae,
                                float* __restrict__ wae) {
    int t = threadIdx.x;
    if (t >= 96) return;
    int d = t / 3, h = t - d * 3;
    float acc = 0.f;
    for (int f = 0; f < 32; ++f) acc += We[d * 96 + h * 32 + f] * ae[h * 32 + f];
    wae[t] = acc;
}

// ---------------------------------------------------------------------------
// CSR build: histogram (also records per-edge rank) -> scan.
// ---------------------------------------------------------------------------
__global__ void hist_rank_kernel(const int* __restrict__ dst, int* __restrict__ cnt,
                                 int* __restrict__ rank, int E) {
    int e = blockIdx.x * blockDim.x + threadIdx.x;
    if (e < E) rank[e] = atomicAdd(&cnt[dst[e]], 1);
}

__global__ void block_sum_kernel(const int* __restrict__ deg, int* __restrict__ bsums, int N) {
    __shared__ int sd[256];
    int t = threadIdx.x;
    int i = blockIdx.x * 256 + t;
    sd[t] = (i < N) ? deg[i] : 0;
    __syncthreads();
    for (int o = 128; o > 0; o >>= 1) {
        if (t < o) sd[t] += sd[t + o];
        __syncthreads();
    }
    if (t == 0) bsums[blockIdx.x] = sd[0];
}

__global__ void scan_bsums_kernel(int* __restrict__ bsums, int nb) {
    __shared__ int a[512], b[512];
    int t = threadIdx.x;
    int v = (t < nb) ? bsums[t] : 0;
    a[t] = v;
    __syncthreads();
    int* in = a;
    int* out = b;
    for (int o = 1; o < 512; o <<= 1) {
        out[t] = in[t] + ((t >= o) ? in[t - o] : 0);
        __syncthreads();
        int* tmp = in; in = out; out = tmp;
    }
    if (t < nb) bsums[t] = in[t] - v;
}

__global__ void scan_expand_kernel(const int* __restrict__ deg, const int* __restrict__ boffs,
                                   int* __restrict__ row_start, int N) {
    __shared__ int a[256], b[256];
    int t = threadIdx.x;
    int i = blockIdx.x * 256 + t;
    int v = (i < N) ? deg[i] : 0;
    a[t] = v;
    __syncthreads();
    int* in = a;
    int* out = b;
    for (int o = 1; o < 256; o <<= 1) {
        out[t] = in[t] + ((t >= o) ? in[t - o] : 0);
        __syncthreads();
        int* tmp = in; in = out; out = tmp;
    }
    if (i < N) row_start[i] = boffs[blockIdx.x] + in[t] - v;
}

__global__ void set_val_kernel(int* __restrict__ p, int v) { p[0] = v; }

// ---------------------------------------------------------------------------
// Register-tiled node transform: 64 nodes/block, W staged in LDS, thread
// computes a 4-row x 6-col tile.  X tile stride DIN+1 (no bank conflicts).
// ---------------------------------------------------------------------------
template <int DIN>
__global__ void ft_elr_tiled_kernel(const void* __restrict__ X, int kind,
                                    const int* __restrict__ mode,
                                    const float* __restrict__ W,
                                    const float* __restrict__ al, const float* __restrict__ ar,
                                    float* __restrict__ ft, float* __restrict__ elr, int N) {
    __shared__ float ws[DIN * 96];
    __shared__ float xb[64 * 97];            // X tile (stride DIN+1), reused as fs (stride 97)
    const int t = threadIdx.x;
    const int base = blockIdx.x * 64;
    const int m = *mode;

    // stage W
    for (int i = t; i < DIN * 96; i += 256) ws[i] = W[i];
    // stage X (zero-pad rows past N)
    for (int i = t; i < 64 * DIN; i += 256) {
        int ln = i / DIN, d = i - ln * DIN;
        int node = base + ln;
        float v = 0.f;
        if (node < N) {
            size_t idx = (size_t)node * DIN + d;
            if (kind == 1)   v = ((const float*)X)[idx];
            else if (m == 0) v = b2f(((const bf16*)X)[idx]);
            else             v = ((const float*)X)[idx];
        }
        xb[ln * (DIN + 1) + d] = v;
    }
    __syncthreads();

    const int cx = t & 15;        // 16 col groups of 6
    const int ry = t >> 4;        // 16 row groups of 4
    const int c0 = cx * 6;
    const int r0 = ry * 4;

    float acc[4][6];
#pragma unroll
    for (int i = 0; i < 4; ++i)
#pragma unroll
        for (int j = 0; j < 6; ++j) acc[i][j] = 0.f;

#pragma unroll 4
    for (int d = 0; d < DIN; ++d) {
        float xv[4];
#pragma unroll
        for (int i = 0; i < 4; ++i) xv[i] = xb[(r0 + i) * (DIN + 1) + d];
        const float* wr = ws + d * 96 + c0;
        float wv[6];
#pragma unroll
        for (int j = 0; j < 6; ++j) wv[j] = wr[j];
#pragma unroll
        for (int i = 0; i < 4; ++i)
#pragma unroll
            for (int j = 0; j < 6; ++j) acc[i][j] += xv[i] * wv[j];
    }
    __syncthreads();   // xb reads done; safe to overwrite as fs

    // accs -> fs (stride 97)
#pragma unroll
    for (int i = 0; i < 4; ++i) {
        float* fr = xb + (r0 + i) * 97 + c0;
#pragma unroll
        for (int j = 0; j < 6; ++j) fr[j] = acc[i][j];
    }
    __syncthreads();

    // coalesced ft write
    for (int i = t; i < 64 * 96; i += 256) {
        int ln = i / 96, c = i - ln * 96;
        int node = base + ln;
        if (node < N) ft[(size_t)node * 96 + c] = xb[ln * 97 + c];
    }
    // el/er dots: 64 nodes x 6 (h x {l,r})
    for (int i = t; i < 384; i += 256) {
        int ln = i / 6, q = i - ln * 6;
        int h = q >> 1, isr = q & 1;
        int node = base + ln;
        if (node < N) {
            const float* av = (isr ? ar : al) + h * 32;
            const float* fr = xb + ln * 97 + h * 32;
            float acc2 = 0.f;
#pragma unroll
            for (int f = 0; f < 32; ++f) acc2 += fr[f] * av[f];
            elr[node * 6 + isr * 3 + h] = acc2;
        }
    }
}

// ---------------------------------------------------------------------------
// Fused scatter + both layers' edge-feature dots.  TWO edges per thread
// (e0 = base+t, e1 = base+256+t, both coalesced) so each wave carries 2x
// independent load/store chains -> 2x outstanding misses (kernel is
// memory-parallelism-bound: 16% BW, 5% VALU, near-minimal traffic).
// ---------------------------------------------------------------------------
__global__ void scatter_edge_kernel(const void* __restrict__ ef, const int* __restrict__ mode,
                                    const float* __restrict__ wae1, const float* __restrict__ wae2,
                                    const int* __restrict__ src, const int* __restrict__ dst,
                                    const int* __restrict__ rank,
                                    const int* __restrict__ row_start,
                                    float4* __restrict__ S, int E) {
    __shared__ float w1[96];
    __shared__ float w2[96];
    int t = threadIdx.x;
    if (t < 96) { w1[t] = wae1[t]; w2[t] = wae2[t]; }
    __syncthreads();
    int base = blockIdx.x * 512;
    int e0 = base + t;
    int e1 = base + 256 + t;
    bool v0 = e0 < E, v1 = e1 < E;
    if (!v0) return;
    int m = *mode;

    // index loads for both edges up front (independent chains)
    int si0 = src[e0], di0 = dst[e0], rk0 = rank[e0];
    int si1 = 0, di1 = 0, rk1 = 0;
    if (v1) { si1 = src[e1]; di1 = dst[e1]; rk1 = rank[e1]; }
    int rs0 = row_start[di0];
    int rs1 = v1 ? row_start[di1] : 0;

    float x0[32], x1[32];
    if (m == 0) {
        const uint4* p0 = (const uint4*)((const uint16_t*)ef + (size_t)e0 * 32);
        const uint4* p1 = (const uint4*)((const uint16_t*)ef + (size_t)e1 * 32);
        uint4 u0[4], u1[4];
#pragma unroll
        for (int q = 0; q < 4; ++q) u0[q] = p0[q];
        if (v1) {
#pragma unroll
            for (int q = 0; q < 4; ++q) u1[q] = p1[q];
        }
#pragma unroll
        for (int q = 0; q < 4; ++q) {
            x0[q * 8 + 0] = bits2f(u0[q].x << 16); x0[q * 8 + 1] = bits2f(u0[q].x & 0xffff0000u);
            x0[q * 8 + 2] = bits2f(u0[q].y << 16); x0[q * 8 + 3] = bits2f(u0[q].y & 0xffff0000u);
            x0[q * 8 + 4] = bits2f(u0[q].z << 16); x0[q * 8 + 5] = bits2f(u0[q].z & 0xffff0000u);
            x0[q * 8 + 6] = bits2f(u0[q].w << 16); x0[q * 8 + 7] = bits2f(u0[q].w & 0xffff0000u);
        }
        if (v1) {
#pragma unroll
            for (int q = 0; q < 4; ++q) {
                x1[q * 8 + 0] = bits2f(u1[q].x << 16); x1[q * 8 + 1] = bits2f(u1[q].x & 0xffff0000u);
                x1[q * 8 + 2] = bits2f(u1[q].y << 16); x1[q * 8 + 3] = bits2f(u1[q].y & 0xffff0000u);
                x1[q * 8 + 4] = bits2f(u1[q].z << 16); x1[q * 8 + 5] = bits2f(u1[q].z & 0xffff0000u);
                x1[q * 8 + 6] = bits2f(u1[q].w << 16); x1[q * 8 + 7] = bits2f(u1[q].w & 0xffff0000u);
            }
        }
    } else {
        const float4* p0 = (const float4*)((const float*)ef + (size_t)e0 * 32);
        const float4* p1 = (const float4*)((const float*)ef + (size_t)e1 * 32);
#pragma unroll
        for (int q = 0; q < 8; ++q) {
            float4 u = p0[q];
            x0[q * 4 + 0] = u.x; x0[q * 4 + 1] = u.y; x0[q * 4 + 2] = u.z; x0[q * 4 + 3] = u.w;
        }
        if (v1) {
#pragma unroll
            for (int q = 0; q < 8; ++q) {
                float u4x = p1[q].x, u4y = p1[q].y, u4z = p1[q].z, u4w = p1[q].w;
                x1[q * 4 + 0] = u4x; x1[q * 4 + 1] = u4y; x1[q * 4 + 2] = u4z; x1[q * 4 + 3] = u4w;
            }
        }
    }

    float a00 = 0.f, a01 = 0.f, a02 = 0.f, c00 = 0.f, c01 = 0.f, c02 = 0.f;
    float a10 = 0.f, a11 = 0.f, a12 = 0.f, c10 = 0.f, c11 = 0.f, c12 = 0.f;
#pragma unroll
    for (int d = 0; d < 32; ++d) {
        float w10 = w1[d * 3 + 0], w11 = w1[d * 3 + 1], w12 = w1[d * 3 + 2];
        float w20 = w2[d * 3 + 0], w21 = w2[d * 3 + 1], w22 = w2[d * 3 + 2];
        float xv0 = x0[d];
        a00 += xv0 * w10; a01 += xv0 * w11; a02 += xv0 * w12;
        c00 += xv0 * w20; c01 += xv0 * w21; c02 += xv0 * w22;
        float xv1 = x1[d];
        a10 += xv1 * w10; a11 += xv1 * w11; a12 += xv1 * w12;
        c10 += xv1 * w20; c11 += xv1 * w21; c12 += xv1 * w22;
    }

    int pos0 = rs0 + rk0;
    S[2 * pos0]     = make_float4(__int_as_float(si0), a00, a01, a02);
    S[2 * pos0 + 1] = make_float4(c00, c01, c02, 0.f);
    if (v1) {
        int pos1 = rs1 + rk1;
        S[2 * pos1]     = make_float4(__int_as_float(si1), a10, a11, a12);
        S[2 * pos1 + 1] = make_float4(c10, c11, c12, 0.f);
    }
}

// ---------------------------------------------------------------------------
// Aggregation with fused edge softmax (both layers).
// ---------------------------------------------------------------------------
__global__ void aggregate_kernel(const float* __restrict__ ft, const float4* __restrict__ S,
                                 const int* __restrict__ row_start,
                                 const float* __restrict__ elr,
                                 const float* __restrict__ bias,
                                 int use_qa, int do_relu,
                                 float* __restrict__ R, int N) {
    int t = threadIdx.x;
    int node = blockIdx.x * 8 + (t >> 5);
    int lane = t & 31;
    if (node >= N) return;
    int beg = row_start[node], end = row_start[node + 1];
    float er0 = elr[node * 6 + 3], er1 = elr[node * 6 + 4], er2 = elr[node * 6 + 5];
    float a0 = 0.f, a1 = 0.f, a2 = 0.f, s0 = 0.f, s1 = 0.f, s2 = 0.f;
    int i = beg;
    for (; i + 4 <= end; i += 4) {
#pragma unroll
        for (int u = 0; u < 4; ++u) {
            float4 qa = S[2 * (i + u)];
            float4 qb = S[2 * (i + u) + 1];
            int sv = __float_as_int(qa.x);
            float ee0, ee1, ee2;
            if (use_qa) { ee0 = qa.y; ee1 = qa.z; ee2 = qa.w; }
            else        { ee0 = qb.x; ee1 = qb.y; ee2 = qb.z; }
            float2 el01 = *(const float2*)(elr + sv * 6);
            float  el2  = elr[sv * 6 + 2];
            float l0 = el01.x + er0 + ee0;
            float l1 = el01.y + er1 + ee1;
            float l2 = el2    + er2 + ee2;
            l0 = (l0 > 0.f) ? l0 : 0.2f * l0;
            l1 = (l1 > 0.f) ? l1 : 0.2f * l1;
            l2 = (l2 > 0.f) ? l2 : 0.2f * l2;
            float e0 = __expf(l0), e1 = __expf(l1), e2 = __expf(l2);
            const float* fr = ft + (size_t)sv * 96;
            a0 += fr[lane] * e0;
            a1 += fr[lane + 32] * e1;
            a2 += fr[lane + 64] * e2;
            s0 += e0; s1 += e1; s2 += e2;
        }
    }
    for (; i < end; ++i) {
        float4 qa = S[2 * i];
        float4 qb = S[2 * i + 1];
        int sv = __float_as_int(qa.x);
        float ee0, ee1, ee2;
        if (use_qa) { ee0 = qa.y; ee1 = qa.z; ee2 = qa.w; }
        else        { ee0 = qb.x; ee1 = qb.y; ee2 = qb.z; }
        float2 el01 = *(const float2*)(elr + sv * 6);
        float  el2  = elr[sv * 6 + 2];
        float l0 = el01.x + er0 + ee0;
        float l1 = el01.y + er1 + ee1;
        float l2 = el2    + er2 + ee2;
        l0 = (l0 > 0.f) ? l0 : 0.2f * l0;
        l1 = (l1 > 0.f) ? l1 : 0.2f * l1;
        l2 = (l2 > 0.f) ? l2 : 0.2f * l2;
        float e0 = __expf(l0), e1 = __expf(l1), e2 = __expf(l2);
        const float* fr = ft + (size_t)sv * 96;
        a0 += fr[lane] * e0;
        a1 += fr[lane + 32] * e1;
        a2 += fr[lane + 64] * e2;
        s0 += e0; s1 += e1; s2 += e2;
    }
    float r0, r1, r2;
    if (end > beg) { r0 = a0 / s0; r1 = a1 / s1; r2 = a2 / s2; }
    else           { r0 = r1 = r2 = 0.f; }
    r0 += bias[lane]; r1 += bias[lane + 32]; r2 += bias[lane + 64];
    if (do_relu) { r0 = fmaxf(r0, 0.f); r1 = fmaxf(r1, 0.f); r2 = fmaxf(r2, 0.f); }
    float* out = R + (size_t)node * 96;
    out[lane] = r0; out[lane + 32] = r1; out[lane + 64] = r2;
}

// Per node (8/block): u[n,c] = h@Wp[0:96,c] + bp[c]; v[n,c] = h@Wp[96:,c]
__global__ void uv_kernel(const float* __restrict__ h, const float* __restrict__ Wp,
                          const float* __restrict__ bp, float* __restrict__ uv, int N) {
    __shared__ float hs[8 * 96];
    int base = blockIdx.x * 8;
    int t = threadIdx.x;
    for (int i = t; i < 768; i += 256) {
        int ln = i / 96, c = i - ln * 96;
        int node = base + ln;
        hs[i] = (node < N) ? h[(size_t)node * 96 + c] : 0.f;
    }
    __syncthreads();
    if (t < 160) {
        int ln = t / 20, q = t - ln * 20;
        int half = q / 10, c = q - half * 10;
        int node = base + ln;
        if (node < N) {
            float acc = half ? 0.f : bp[c];
            const float* hr = hs + ln * 96;
            const float* wcol = Wp + half * 960 + c;
            for (int j = 0; j < 96; ++j) acc += hr[j] * wcol[j * 10];
            uv[node * 20 + q] = acc;
        }
    }
}

// Two edges per thread (same MLP argument as scatter): per-edge work is two
// random 40/80B gathers from L2-resident uv + one sequential store.
__global__ void score_kernel(const float* __restrict__ uv, const int* __restrict__ src,
                             const int* __restrict__ dst, const int* __restrict__ mode,
                             void* __restrict__ out, int E) {
    int t = threadIdx.x;
    int base = blockIdx.x * 512;
    int e0 = base + t;
    int e1 = base + 256 + t;
    bool v1 = e1 < E;
    if (e0 >= E) return;
    int si0 = src[e0], di0 = dst[e0];
    int si1 = 0, di1 = 0;
    if (v1) { si1 = src[e1]; di1 = dst[e1]; }
    const float* u0 = uv + (size_t)si0 * 20;
    const float* w0 = uv + (size_t)di0 * 20 + 10;
    const float* u1 = uv + (size_t)si1 * 20;
    const float* w1 = uv + (size_t)di1 * 20 + 10;
    float r0[10], r1[10];
#pragma unroll
    for (int c = 0; c < 10; ++c) r0[c] = u0[c] + w0[c];
    if (v1) {
#pragma unroll
        for (int c = 0; c < 10; ++c) r1[c] = u1[c] + w1[c];
    }
    if (*mode == 0) {
        bf16 o0[10];
#pragma unroll
        for (int c = 0; c < 10; ++c) o0[c] = __float2bfloat16(r0[c]);
        uint32_t* po0 = (uint32_t*)((bf16*)out + (size_t)e0 * 10);
        const uint32_t* ps0 = (const uint32_t*)o0;
#pragma unroll
        for (int q = 0; q < 5; ++q) po0[q] = ps0[q];
        if (v1) {
            bf16 o1[10];
#pragma unroll
            for (int c = 0; c < 10; ++c) o1[c] = __float2bfloat16(r1[c]);
            uint32_t* po1 = (uint32_t*)((bf16*)out + (size_t)e1 * 10);
            const uint32_t* ps1 = (const uint32_t*)o1;
#pragma unroll
            for (int q = 0; q < 5; ++q) po1[q] = ps1[q];
        }
    } else {
        float2* po0 = (float2*)((float*)out + (size_t)e0 * 10);
#pragma unroll
        for (int q = 0; q < 5; ++q) po0[q] = make_float2(r0[2 * q], r0[2 * q + 1]);
        if (v1) {
            float2* po1 = (float2*)((float*)out + (size_t)e1 * 10);
#pragma unroll
            for (int q = 0; q < 5; ++q) po1[q] = make_float2(r1[2 * q], r1[2 * q + 1]);
        }
    }
}

extern "C" void kernel_launch(void* const* d_in, const int* in_sizes, int n_in,
                              void* d_out, int out_size, void* d_ws, size_t ws_size,
                              hipStream_t stream) {
    const void* nfeats = d_in[0];
    const void* efeats = d_in[1];
    const int* src = (const int*)d_in[2];
    const int* dst = (const int*)d_in[3];

    const int N = in_sizes[0] / 64;
    const int E = in_sizes[2];

    // ---- workspace (~138 MB) ----
    char* w = (char*)d_ws;
    auto alloc = [&](size_t bytes) {
        void* p = (void*)w;
        w += (bytes + 255) & ~(size_t)255;
        return p;
    };
    int*    flag      = (int*)alloc(256);
    float*  pbuf      = (float*)alloc((size_t)24202 * 4);
    float*  wae1      = (float*)alloc(96 * 4);
    float*  wae2      = (float*)alloc(96 * 4);
    float*  R         = (float*)alloc((size_t)N * 96 * 4);   // h (aggregate out)
    float*  F         = (float*)alloc((size_t)N * 96 * 4);   // ft per layer
    float4* S         = (float4*)alloc((size_t)E * 32);      // {src, ee1*3}{ee2*3, pad}
    float*  elr       = (float*)alloc((size_t)N * 6 * 4);
    int*    row_start = (int*)alloc((size_t)(N + 1) * 4);
    int*    cnt       = (int*)alloc((size_t)N * 4);
    int*    bsums     = (int*)alloc(512 * 4);
    int*    rank      = (int*)alloc((size_t)E * 4);
    float*  uv        = (float*)S;                            // S dead after layer 2

    const int ns[14] = {64*96, 32*96, 96, 96, 96, 96, 96*96, 32*96, 96, 96, 96, 96, 192*10, 10};
    ParamTable T;
    int off = 0;
    for (int k = 0; k < 14; ++k) { T.src[k] = d_in[4 + k]; T.off[k] = off; off += ns[k]; }
    T.off[14] = off;
    float* W1f  = pbuf + T.off[0];
    float* We1f = pbuf + T.off[1];
    float* al1f = pbuf + T.off[2];
    float* ar1f = pbuf + T.off[3];
    float* ae1f = pbuf + T.off[4];
    float* b1f  = pbuf + T.off[5];
    float* W2f  = pbuf + T.off[6];
    float* We2f = pbuf + T.off[7];
    float* al2f = pbuf + T.off[8];
    float* ar2f = pbuf + T.off[9];
    float* ae2f = pbuf + T.off[10];
    float* b2f_ = pbuf + T.off[11];
    float* Wpf  = pbuf + T.off[12];
    float* bpf  = pbuf + T.off[13];

    dim3 b256(256);
    int eblocks    = (E + 255) / 256;
    int eblocks2   = (E + 511) / 512;
    int nodeBlocks = (N + 7) / 8;
    int tileBlocks = (N + 63) / 64;
    int nb         = (N + 255) / 256;

    hipLaunchKernelGGL(detect_mode_kernel, dim3(1), dim3(64), 0, stream,
                       (const uint16_t*)nfeats, flag);
    hipLaunchKernelGGL(convert_params_kernel, dim3((off + 255) / 256), b256, 0, stream,
                       T, flag, pbuf);
    hipLaunchKernelGGL(fold_wae_kernel, dim3(1), dim3(128), 0, stream, We1f, ae1f, wae1);
    hipLaunchKernelGGL(fold_wae_kernel, dim3(1), dim3(128), 0, stream, We2f, ae2f, wae2);

    // ---- CSR offsets + per-edge rank ----
    hipMemsetAsync(cnt, 0, (size_t)N * 4, stream);
    hipLaunchKernelGGL(hist_rank_kernel, dim3(eblocks), b256, 0, stream, dst, cnt, rank, E);
    hipLaunchKernelGGL(block_sum_kernel, dim3(nb), b256, 0, stream, cnt, bsums, N);
    hipLaunchKernelGGL(scan_bsums_kernel, dim3(1), dim3(512), 0, stream, bsums, nb);
    hipLaunchKernelGGL(scan_expand_kernel, dim3(nb), b256, 0, stream, cnt, bsums, row_start, N);
    hipLaunchKernelGGL(set_val_kernel, dim3(1), dim3(1), 0, stream, row_start + N, E);

    // ---- fused scatter + both layers' edge-feature dots (ONE efeats sweep) ----
    hipLaunchKernelGGL(scatter_edge_kernel, dim3(eblocks2), b256, 0, stream,
                       efeats, flag, wae1, wae2, src, dst, rank, row_start, S, E);

    // ---- layer 1 ----
    hipLaunchKernelGGL((ft_elr_tiled_kernel<64>), dim3(tileBlocks), b256, 0, stream,
                       nfeats, 0, flag, W1f, al1f, ar1f, F, elr, N);
    hipLaunchKernelGGL(aggregate_kernel, dim3(nodeBlocks), b256, 0, stream,
                       F, S, row_start, elr, b1f, 1, 1, R, N);

    // ---- layer 2 ----
    hipLaunchKernelGGL((ft_elr_tiled_kernel<96>), dim3(tileBlocks), b256, 0, stream,
                       (const void*)R, 1, flag, W2f, al2f, ar2f, F, elr, N);
    hipLaunchKernelGGL(aggregate_kernel, dim3(nodeBlocks), b256, 0, stream,
                       F, S, row_start, elr, b2f_, 0, 0, R, N);

    // ---- predictor ----
    hipLaunchKernelGGL(uv_kernel, dim3(nodeBlocks), b256, 0, stream, R, Wpf, bpf, uv, N);
    hipLaunchKernelGGL(score_kernel, dim3(eblocks2), b256, 0, stream,
                       uv, src, dst, flag, d_out, E);
}

// Round 5
// 1042.981 us; speedup vs baseline: 1.1697x; 1.1697x over previous
//
#include <hip/hip_runtime.h>
#include <hip/hip_bf16.h>
#include <stdint.h>

typedef __hip_bfloat16 bf16;

__device__ __forceinline__ float b2f(bf16 x) { return __bfloat162float(x); }
__device__ __forceinline__ float bits2f(uint32_t u) {
    union { uint32_t i; float f; } c; c.i = u; return c.f;
}

// ---------------------------------------------------------------------------
// Mode detection: 0 = bf16 external tensors, 1 = f32.
// ---------------------------------------------------------------------------
__global__ void detect_mode_kernel(const uint16_t* __restrict__ nf, int* __restrict__ flag) {
    if (threadIdx.x != 0 || blockIdx.x != 0) return;
    int sane = 0;
    for (int i = 0; i < 256; ++i) {
        uint32_t u = nf[2 * i];
        float a = fabsf(bits2f(u << 16));
        if (a == 0.f || (a > 1e-5f && a < 100.f)) ++sane;
    }
    flag[0] = (sane >= 128) ? 0 : 1;
}

struct ParamTable {
    const void* src[14];
    int off[15];
};

__global__ void convert_params_kernel(ParamTable T, const int* __restrict__ mode,
                                      float* __restrict__ out) {
    int i = blockIdx.x * blockDim.x + threadIdx.x;
    if (i >= T.off[14]) return;
    int k = 0;
    while (k < 13 && i >= T.off[k + 1]) ++k;
    int j = i - T.off[k];
    out[i] = (*mode == 0) ? b2f(((const bf16*)T.src[k])[j]) : ((const float*)T.src[k])[j];
}

// wae[d*3+h] = sum_f We[d*96 + h*32 + f] * ae[h*32 + f]
__global__ void fold_wae_kernel(const float* __restrict__ We, const float* __restrict__ ae,
                                float* __restrict__ wae) {
    int t = threadIdx.x;
    if (t >= 96) return;
    int d = t / 3, h = t - d * 3;
    float acc = 0.f;
    for (int f = 0; f < 32; ++f) acc += We[d * 96 + h * 32 + f] * ae[h * 32 + f];
    wae[t] = acc;
}

// ---------------------------------------------------------------------------
// CSR build: histogram (also records per-edge rank) -> scan.
// ---------------------------------------------------------------------------
__global__ void hist_rank_kernel(const int* __restrict__ dst, int* __restrict__ cnt,
                                 int* __restrict__ rank, int E) {
    int e = blockIdx.x * blockDim.x + threadIdx.x;
    if (e < E) rank[e] = atomicAdd(&cnt[dst[e]], 1);
}

__global__ void block_sum_kernel(const int* __restrict__ deg, int* __restrict__ bsums, int N) {
    __shared__ int sd[256];
    int t = threadIdx.x;
    int i = blockIdx.x * 256 + t;
    sd[t] = (i < N) ? deg[i] : 0;
    __syncthreads();
    for (int o = 128; o > 0; o >>= 1) {
        if (t < o) sd[t] += sd[t + o];
        __syncthreads();
    }
    if (t == 0) bsums[blockIdx.x] = sd[0];
}

__global__ void scan_bsums_kernel(int* __restrict__ bsums, int nb) {
    __shared__ int a[512], b[512];
    int t = threadIdx.x;
    int v = (t < nb) ? bsums[t] : 0;
    a[t] = v;
    __syncthreads();
    int* in = a;
    int* out = b;
    for (int o = 1; o < 512; o <<= 1) {
        out[t] = in[t] + ((t >= o) ? in[t - o] : 0);
        __syncthreads();
        int* tmp = in; in = out; out = tmp;
    }
    if (t < nb) bsums[t] = in[t] - v;
}

__global__ void scan_expand_kernel(const int* __restrict__ deg, const int* __restrict__ boffs,
                                   int* __restrict__ row_start, int N) {
    __shared__ int a[256], b[256];
    int t = threadIdx.x;
    int i = blockIdx.x * 256 + t;
    int v = (i < N) ? deg[i] : 0;
    a[t] = v;
    __syncthreads();
    int* in = a;
    int* out = b;
    for (int o = 1; o < 256; o <<= 1) {
        out[t] = in[t] + ((t >= o) ? in[t - o] : 0);
        __syncthreads();
        int* tmp = in; in = out; out = tmp;
    }
    if (i < N) row_start[i] = boffs[blockIdx.x] + in[t] - v;
}

__global__ void set_val_kernel(int* __restrict__ p, int v) { p[0] = v; }

// ---------------------------------------------------------------------------
// Register-tiled node transform: 64 nodes/block, W staged in LDS, thread
// computes a 4-row x 6-col tile.  X tile stride DIN+1 (no bank conflicts).
// ---------------------------------------------------------------------------
template <int DIN>
__global__ void ft_elr_tiled_kernel(const void* __restrict__ X, int kind,
                                    const int* __restrict__ mode,
                                    const float* __restrict__ W,
                                    const float* __restrict__ al, const float* __restrict__ ar,
                                    float* __restrict__ ft, float* __restrict__ elr, int N) {
    __shared__ float ws[DIN * 96];
    __shared__ float xb[64 * 97];            // X tile (stride DIN+1), reused as fs (stride 97)
    const int t = threadIdx.x;
    const int base = blockIdx.x * 64;
    const int m = *mode;

    // stage W
    for (int i = t; i < DIN * 96; i += 256) ws[i] = W[i];
    // stage X (zero-pad rows past N)
    for (int i = t; i < 64 * DIN; i += 256) {
        int ln = i / DIN, d = i - ln * DIN;
        int node = base + ln;
        float v = 0.f;
        if (node < N) {
            size_t idx = (size_t)node * DIN + d;
            if (kind == 1)   v = ((const float*)X)[idx];
            else if (m == 0) v = b2f(((const bf16*)X)[idx]);
            else             v = ((const float*)X)[idx];
        }
        xb[ln * (DIN + 1) + d] = v;
    }
    __syncthreads();

    const int cx = t & 15;        // 16 col groups of 6
    const int ry = t >> 4;        // 16 row groups of 4
    const int c0 = cx * 6;
    const int r0 = ry * 4;

    float acc[4][6];
#pragma unroll
    for (int i = 0; i < 4; ++i)
#pragma unroll
        for (int j = 0; j < 6; ++j) acc[i][j] = 0.f;

#pragma unroll 4
    for (int d = 0; d < DIN; ++d) {
        float xv[4];
#pragma unroll
        for (int i = 0; i < 4; ++i) xv[i] = xb[(r0 + i) * (DIN + 1) + d];
        const float* wr = ws + d * 96 + c0;
        float wv[6];
#pragma unroll
        for (int j = 0; j < 6; ++j) wv[j] = wr[j];
#pragma unroll
        for (int i = 0; i < 4; ++i)
#pragma unroll
            for (int j = 0; j < 6; ++j) acc[i][j] += xv[i] * wv[j];
    }
    __syncthreads();   // xb reads done; safe to overwrite as fs

    // accs -> fs (stride 97)
#pragma unroll
    for (int i = 0; i < 4; ++i) {
        float* fr = xb + (r0 + i) * 97 + c0;
#pragma unroll
        for (int j = 0; j < 6; ++j) fr[j] = acc[i][j];
    }
    __syncthreads();

    // coalesced ft write
    for (int i = t; i < 64 * 96; i += 256) {
        int ln = i / 96, c = i - ln * 96;
        int node = base + ln;
        if (node < N) ft[(size_t)node * 96 + c] = xb[ln * 97 + c];
    }
    // el/er dots: 64 nodes x 6 (h x {l,r})
    for (int i = t; i < 384; i += 256) {
        int ln = i / 6, q = i - ln * 6;
        int h = q >> 1, isr = q & 1;
        int node = base + ln;
        if (node < N) {
            const float* av = (isr ? ar : al) + h * 32;
            const float* fr = xb + ln * 97 + h * 32;
            float acc2 = 0.f;
#pragma unroll
            for (int f = 0; f < 32; ++f) acc2 += fr[f] * av[f];
            elr[node * 6 + isr * 3 + h] = acc2;
        }
    }
}

// ---------------------------------------------------------------------------
// Fused scatter + both layers' edge-feature dots.  TWO edges per thread for
// 2x memory-level parallelism.  Register-pressure-safe version of R4's
// attempt: raw uint4 words stay in registers (32 VGPR for both edges) and
// bf16->f32 conversion happens inside the FMA loop with compile-time
// indices -- no x[32] arrays, no scratch spill.  __launch_bounds__(256,4)
// caps VGPR at 128 (4 waves/SIMD, >= achieved occupancy).
// ---------------------------------------------------------------------------
__global__ __launch_bounds__(256, 4)
void scatter_edge_kernel(const void* __restrict__ ef, const int* __restrict__ mode,
                         const float* __restrict__ wae1, const float* __restrict__ wae2,
                         const int* __restrict__ src, const int* __restrict__ dst,
                         const int* __restrict__ rank,
                         const int* __restrict__ row_start,
                         float4* __restrict__ S, int E) {
    __shared__ float w1[96];
    __shared__ float w2[96];
    int t = threadIdx.x;
    if (t < 96) { w1[t] = wae1[t]; w2[t] = wae2[t]; }
    __syncthreads();
    int base = blockIdx.x * 512;
    int e0 = base + t;
    if (e0 >= E) return;
    int e1 = base + 256 + t;
    bool v1 = e1 < E;
    int e1c = v1 ? e1 : e0;       // clamped: loads always valid, store predicated
    int m = *mode;

    // index loads for both edges up front (independent chains)
    int si0 = src[e0], di0 = dst[e0], rk0 = rank[e0];
    int si1 = src[e1c], di1 = dst[e1c], rk1 = rank[e1c];
    int rs0 = row_start[di0];
    int rs1 = row_start[di1];

    float a00 = 0.f, a01 = 0.f, a02 = 0.f, c00 = 0.f, c01 = 0.f, c02 = 0.f;
    float a10 = 0.f, a11 = 0.f, a12 = 0.f, c10 = 0.f, c11 = 0.f, c12 = 0.f;

    if (m == 0) {
        const uint4* p0 = (const uint4*)((const uint16_t*)ef + (size_t)e0 * 32);
        const uint4* p1 = (const uint4*)((const uint16_t*)ef + (size_t)e1c * 32);
        uint4 u0[4], u1[4];
#pragma unroll
        for (int q = 0; q < 4; ++q) u0[q] = p0[q];
#pragma unroll
        for (int q = 0; q < 4; ++q) u1[q] = p1[q];
#pragma unroll
        for (int q = 0; q < 4; ++q) {
            uint32_t ws0[4] = {u0[q].x, u0[q].y, u0[q].z, u0[q].w};
            uint32_t ws1[4] = {u1[q].x, u1[q].y, u1[q].z, u1[q].w};
#pragma unroll
            for (int k = 0; k < 4; ++k) {
                int d = q * 8 + k * 2;
                float w1a = w1[d * 3 + 0], w1b = w1[d * 3 + 1], w1c = w1[d * 3 + 2];
                float w2a = w2[d * 3 + 0], w2b = w2[d * 3 + 1], w2c = w2[d * 3 + 2];
                float w1d = w1[d * 3 + 3], w1e = w1[d * 3 + 4], w1f = w1[d * 3 + 5];
                float w2d = w2[d * 3 + 3], w2e = w2[d * 3 + 4], w2f = w2[d * 3 + 5];
                float lo0 = bits2f(ws0[k] << 16), hi0 = bits2f(ws0[k] & 0xffff0000u);
                float lo1 = bits2f(ws1[k] << 16), hi1 = bits2f(ws1[k] & 0xffff0000u);
                a00 += lo0 * w1a + hi0 * w1d;
                a01 += lo0 * w1b + hi0 * w1e;
                a02 += lo0 * w1c + hi0 * w1f;
                c00 += lo0 * w2a + hi0 * w2d;
                c01 += lo0 * w2b + hi0 * w2e;
                c02 += lo0 * w2c + hi0 * w2f;
                a10 += lo1 * w1a + hi1 * w1d;
                a11 += lo1 * w1b + hi1 * w1e;
                a12 += lo1 * w1c + hi1 * w1f;
                c10 += lo1 * w2a + hi1 * w2d;
                c11 += lo1 * w2b + hi1 * w2e;
                c12 += lo1 * w2c + hi1 * w2f;
            }
        }
    } else {
        const float4* p0 = (const float4*)((const float*)ef + (size_t)e0 * 32);
        const float4* p1 = (const float4*)((const float*)ef + (size_t)e1c * 32);
        // two half-chunks of 16 floats each to bound live registers
#pragma unroll
        for (int hf = 0; hf < 2; ++hf) {
            float4 f0[4], f1[4];
#pragma unroll
            for (int q = 0; q < 4; ++q) f0[q] = p0[hf * 4 + q];
#pragma unroll
            for (int q = 0; q < 4; ++q) f1[q] = p1[hf * 4 + q];
#pragma unroll
            for (int q = 0; q < 4; ++q) {
                float vs0[4] = {f0[q].x, f0[q].y, f0[q].z, f0[q].w};
                float vs1[4] = {f1[q].x, f1[q].y, f1[q].z, f1[q].w};
#pragma unroll
                for (int j = 0; j < 4; ++j) {
                    int d = hf * 16 + q * 4 + j;
                    float w1a = w1[d * 3 + 0], w1b = w1[d * 3 + 1], w1c = w1[d * 3 + 2];
                    float w2a = w2[d * 3 + 0], w2b = w2[d * 3 + 1], w2c = w2[d * 3 + 2];
                    float x0v = vs0[j], x1v = vs1[j];
                    a00 += x0v * w1a; a01 += x0v * w1b; a02 += x0v * w1c;
                    c00 += x0v * w2a; c01 += x0v * w2b; c02 += x0v * w2c;
                    a10 += x1v * w1a; a11 += x1v * w1b; a12 += x1v * w1c;
                    c10 += x1v * w2a; c11 += x1v * w2b; c12 += x1v * w2c;
                }
            }
        }
    }

    int pos0 = rs0 + rk0;
    S[2 * pos0]     = make_float4(__int_as_float(si0), a00, a01, a02);
    S[2 * pos0 + 1] = make_float4(c00, c01, c02, 0.f);
    if (v1) {
        int pos1 = rs1 + rk1;
        S[2 * pos1]     = make_float4(__int_as_float(si1), a10, a11, a12);
        S[2 * pos1 + 1] = make_float4(c10, c11, c12, 0.f);
    }
}

// ---------------------------------------------------------------------------
// Aggregation with fused edge softmax (both layers).
// ---------------------------------------------------------------------------
__global__ void aggregate_kernel(const float* __restrict__ ft, const float4* __restrict__ S,
                                 const int* __restrict__ row_start,
                                 const float* __restrict__ elr,
                                 const float* __restrict__ bias,
                                 int use_qa, int do_relu,
                                 float* __restrict__ R, int N) {
    int t = threadIdx.x;
    int node = blockIdx.x * 8 + (t >> 5);
    int lane = t & 31;
    if (node >= N) return;
    int beg = row_start[node], end = row_start[node + 1];
    float er0 = elr[node * 6 + 3], er1 = elr[node * 6 + 4], er2 = elr[node * 6 + 5];
    float a0 = 0.f, a1 = 0.f, a2 = 0.f, s0 = 0.f, s1 = 0.f, s2 = 0.f;
    int i = beg;
    for (; i + 4 <= end; i += 4) {
#pragma unroll
        for (int u = 0; u < 4; ++u) {
            float4 qa = S[2 * (i + u)];
            float4 qb = S[2 * (i + u) + 1];
            int sv = __float_as_int(qa.x);
            float ee0, ee1, ee2;
            if (use_qa) { ee0 = qa.y; ee1 = qa.z; ee2 = qa.w; }
            else        { ee0 = qb.x; ee1 = qb.y; ee2 = qb.z; }
            float2 el01 = *(const float2*)(elr + sv * 6);
            float  el2  = elr[sv * 6 + 2];
            float l0 = el01.x + er0 + ee0;
            float l1 = el01.y + er1 + ee1;
            float l2 = el2    + er2 + ee2;
            l0 = (l0 > 0.f) ? l0 : 0.2f * l0;
            l1 = (l1 > 0.f) ? l1 : 0.2f * l1;
            l2 = (l2 > 0.f) ? l2 : 0.2f * l2;
            float e0 = __expf(l0), e1 = __expf(l1), e2 = __expf(l2);
            const float* fr = ft + (size_t)sv * 96;
            a0 += fr[lane] * e0;
            a1 += fr[lane + 32] * e1;
            a2 += fr[lane + 64] * e2;
            s0 += e0; s1 += e1; s2 += e2;
        }
    }
    for (; i < end; ++i) {
        float4 qa = S[2 * i];
        float4 qb = S[2 * i + 1];
        int sv = __float_as_int(qa.x);
        float ee0, ee1, ee2;
        if (use_qa) { ee0 = qa.y; ee1 = qa.z; ee2 = qa.w; }
        else        { ee0 = qb.x; ee1 = qb.y; ee2 = qb.z; }
        float2 el01 = *(const float2*)(elr + sv * 6);
        float  el2  = elr[sv * 6 + 2];
        float l0 = el01.x + er0 + ee0;
        float l1 = el01.y + er1 + ee1;
        float l2 = el2    + er2 + ee2;
        l0 = (l0 > 0.f) ? l0 : 0.2f * l0;
        l1 = (l1 > 0.f) ? l1 : 0.2f * l1;
        l2 = (l2 > 0.f) ? l2 : 0.2f * l2;
        float e0 = __expf(l0), e1 = __expf(l1), e2 = __expf(l2);
        const float* fr = ft + (size_t)sv * 96;
        a0 += fr[lane] * e0;
        a1 += fr[lane + 32] * e1;
        a2 += fr[lane + 64] * e2;
        s0 += e0; s1 += e1; s2 += e2;
    }
    float r0, r1, r2;
    if (end > beg) { r0 = a0 / s0; r1 = a1 / s1; r2 = a2 / s2; }
    else           { r0 = r1 = r2 = 0.f; }
    r0 += bias[lane]; r1 += bias[lane + 32]; r2 += bias[lane + 64];
    if (do_relu) { r0 = fmaxf(r0, 0.f); r1 = fmaxf(r1, 0.f); r2 = fmaxf(r2, 0.f); }
    float* out = R + (size_t)node * 96;
    out[lane] = r0; out[lane + 32] = r1; out[lane + 64] = r2;
}

// Per node (8/block): u[n,c] = h@Wp[0:96,c] + bp[c]; v[n,c] = h@Wp[96:,c]
__global__ void uv_kernel(const float* __restrict__ h, const float* __restrict__ Wp,
                          const float* __restrict__ bp, float* __restrict__ uv, int N) {
    __shared__ float hs[8 * 96];
    int base = blockIdx.x * 8;
    int t = threadIdx.x;
    for (int i = t; i < 768; i += 256) {
        int ln = i / 96, c = i - ln * 96;
        int node = base + ln;
        hs[i] = (node < N) ? h[(size_t)node * 96 + c] : 0.f;
    }
    __syncthreads();
    if (t < 160) {
        int ln = t / 20, q = t - ln * 20;
        int half = q / 10, c = q - half * 10;
        int node = base + ln;
        if (node < N) {
            float acc = half ? 0.f : bp[c];
            const float* hr = hs + ln * 96;
            const float* wcol = Wp + half * 960 + c;
            for (int j = 0; j < 96; ++j) acc += hr[j] * wcol[j * 10];
            uv[node * 20 + q] = acc;
        }
    }
}

// Two edges per thread: per-edge work is two random 40B gathers from
// L2-resident uv + one sequential store.
__global__ void score_kernel(const float* __restrict__ uv, const int* __restrict__ src,
                             const int* __restrict__ dst, const int* __restrict__ mode,
                             void* __restrict__ out, int E) {
    int t = threadIdx.x;
    int base = blockIdx.x * 512;
    int e0 = base + t;
    int e1 = base + 256 + t;
    bool v1 = e1 < E;
    if (e0 >= E) return;
    int e1c = v1 ? e1 : e0;
    int si0 = src[e0], di0 = dst[e0];
    int si1 = src[e1c], di1 = dst[e1c];
    const float* u0 = uv + (size_t)si0 * 20;
    const float* w0 = uv + (size_t)di0 * 20 + 10;
    const float* u1 = uv + (size_t)si1 * 20;
    const float* w1 = uv + (size_t)di1 * 20 + 10;
    float r0[10], r1[10];
#pragma unroll
    for (int c = 0; c < 10; ++c) r0[c] = u0[c] + w0[c];
#pragma unroll
    for (int c = 0; c < 10; ++c) r1[c] = u1[c] + w1[c];
    if (*mode == 0) {
        bf16 o0[10];
#pragma unroll
        for (int c = 0; c < 10; ++c) o0[c] = __float2bfloat16(r0[c]);
        uint32_t* po0 = (uint32_t*)((bf16*)out + (size_t)e0 * 10);
        const uint32_t* ps0 = (const uint32_t*)o0;
#pragma unroll
        for (int q = 0; q < 5; ++q) po0[q] = ps0[q];
        if (v1) {
            bf16 o1[10];
#pragma unroll
            for (int c = 0; c < 10; ++c) o1[c] = __float2bfloat16(r1[c]);
            uint32_t* po1 = (uint32_t*)((bf16*)out + (size_t)e1 * 10);
            const uint32_t* ps1 = (const uint32_t*)o1;
#pragma unroll
            for (int q = 0; q < 5; ++q) po1[q] = ps1[q];
        }
    } else {
        float2* po0 = (float2*)((float*)out + (size_t)e0 * 10);
#pragma unroll
        for (int q = 0; q < 5; ++q) po0[q] = make_float2(r0[2 * q], r0[2 * q + 1]);
        if (v1) {
            float2* po1 = (float2*)((float*)out + (size_t)e1 * 10);
#pragma unroll
            for (int q = 0; q < 5; ++q) po1[q] = make_float2(r1[2 * q], r1[2 * q + 1]);
        }
    }
}

extern "C" void kernel_launch(void* const* d_in, const int* in_sizes, int n_in,
                              void* d_out, int out_size, void* d_ws, size_t ws_size,
                              hipStream_t stream) {
    const void* nfeats = d_in[0];
    const void* efeats = d_in[1];
    const int* src = (const int*)d_in[2];
    const int* dst = (const int*)d_in[3];

    const int N = in_sizes[0] / 64;
    const int E = in_sizes[2];

    // ---- workspace (~138 MB) ----
    char* w = (char*)d_ws;
    auto alloc = [&](size_t bytes) {
        void* p = (void*)w;
        w += (bytes + 255) & ~(size_t)255;
        return p;
    };
    int*    flag      = (int*)alloc(256);
    float*  pbuf      = (float*)alloc((size_t)24202 * 4);
    float*  wae1      = (float*)alloc(96 * 4);
    float*  wae2      = (float*)alloc(96 * 4);
    float*  R         = (float*)alloc((size_t)N * 96 * 4);   // h (aggregate out)
    float*  F         = (float*)alloc((size_t)N * 96 * 4);   // ft per layer
    float4* S         = (float4*)alloc((size_t)E * 32);      // {src, ee1*3}{ee2*3, pad}
    float*  elr       = (float*)alloc((size_t)N * 6 * 4);
    int*    row_start = (int*)alloc((size_t)(N + 1) * 4);
    int*    cnt       = (int*)alloc((size_t)N * 4);
    int*    bsums     = (int*)alloc(512 * 4);
    int*    rank      = (int*)alloc((size_t)E * 4);
    float*  uv        = (float*)S;                            // S dead after layer 2

    const int ns[14] = {64*96, 32*96, 96, 96, 96, 96, 96*96, 32*96, 96, 96, 96, 96, 192*10, 10};
    ParamTable T;
    int off = 0;
    for (int k = 0; k < 14; ++k) { T.src[k] = d_in[4 + k]; T.off[k] = off; off += ns[k]; }
    T.off[14] = off;
    float* W1f  = pbuf + T.off[0];
    float* We1f = pbuf + T.off[1];
    float* al1f = pbuf + T.off[2];
    float* ar1f = pbuf + T.off[3];
    float* ae1f = pbuf + T.off[4];
    float* b1f  = pbuf + T.off[5];
    float* W2f  = pbuf + T.off[6];
    float* We2f = pbuf + T.off[7];
    float* al2f = pbuf + T.off[8];
    float* ar2f = pbuf + T.off[9];
    float* ae2f = pbuf + T.off[10];
    float* b2f_ = pbuf + T.off[11];
    float* Wpf  = pbuf + T.off[12];
    float* bpf  = pbuf + T.off[13];

    dim3 b256(256);
    int eblocks    = (E + 255) / 256;
    int eblocks2   = (E + 511) / 512;
    int nodeBlocks = (N + 7) / 8;
    int tileBlocks = (N + 63) / 64;
    int nb         = (N + 255) / 256;

    hipLaunchKernelGGL(detect_mode_kernel, dim3(1), dim3(64), 0, stream,
                       (const uint16_t*)nfeats, flag);
    hipLaunchKernelGGL(convert_params_kernel, dim3((off + 255) / 256), b256, 0, stream,
                       T, flag, pbuf);
    hipLaunchKernelGGL(fold_wae_kernel, dim3(1), dim3(128), 0, stream, We1f, ae1f, wae1);
    hipLaunchKernelGGL(fold_wae_kernel, dim3(1), dim3(128), 0, stream, We2f, ae2f, wae2);

    // ---- CSR offsets + per-edge rank ----
    hipMemsetAsync(cnt, 0, (size_t)N * 4, stream);
    hipLaunchKernelGGL(hist_rank_kernel, dim3(eblocks), b256, 0, stream, dst, cnt, rank, E);
    hipLaunchKernelGGL(block_sum_kernel, dim3(nb), b256, 0, stream, cnt, bsums, N);
    hipLaunchKernelGGL(scan_bsums_kernel, dim3(1), dim3(512), 0, stream, bsums, nb);
    hipLaunchKernelGGL(scan_expand_kernel, dim3(nb), b256, 0, stream, cnt, bsums, row_start, N);
    hipLaunchKernelGGL(set_val_kernel, dim3(1), dim3(1), 0, stream, row_start + N, E);

    // ---- fused scatter + both layers' edge-feature dots (ONE efeats sweep) ----
    hipLaunchKernelGGL(scatter_edge_kernel, dim3(eblocks2), b256, 0, stream,
                       efeats, flag, wae1, wae2, src, dst, rank, row_start, S, E);

    // ---- layer 1 ----
    hipLaunchKernelGGL((ft_elr_tiled_kernel<64>), dim3(tileBlocks), b256, 0, stream,
                       nfeats, 0, flag, W1f, al1f, ar1f, F, elr, N);
    hipLaunchKernelGGL(aggregate_kernel, dim3(nodeBlocks), b256, 0, stream,
                       F, S, row_start, elr, b1f, 1, 1, R, N);

    // ---- layer 2 ----
    hipLaunchKernelGGL((ft_elr_tiled_kernel<96>), dim3(tileBlocks), b256, 0, stream,
                       (const void*)R, 1, flag, W2f, al2f, ar2f, F, elr, N);
    hipLaunchKernelGGL(aggregate_kernel, dim3(nodeBlocks), b256, 0, stream,
                       F, S, row_start, elr, b2f_, 0, 0, R, N);

    // ---- predictor ----
    hipLaunchKernelGGL(uv_kernel, dim3(nodeBlocks), b256, 0, stream, R, Wpf, bpf, uv, N);
    hipLaunchKernelGGL(score_kernel, dim3(eblocks2), b256, 0, stream,
                       uv, src, dst, flag, d_out, E);
}

// Round 6
// 1025.149 us; speedup vs baseline: 1.1900x; 1.0174x over previous
//
#include <hip/hip_runtime.h>
#include <hip/hip_bf16.h>
#include <stdint.h>

typedef __hip_bfloat16 bf16;

__device__ __forceinline__ float b2f(bf16 x) { return __bfloat162float(x); }
__device__ __forceinline__ float bits2f(uint32_t u) {
    union { uint32_t i; float f; } c; c.i = u; return c.f;
}

// ---------------------------------------------------------------------------
// Mode detection: 0 = bf16 external tensors, 1 = f32.
// ---------------------------------------------------------------------------
__global__ void detect_mode_kernel(const uint16_t* __restrict__ nf, int* __restrict__ flag) {
    if (threadIdx.x != 0 || blockIdx.x != 0) return;
    int sane = 0;
    for (int i = 0; i < 256; ++i) {
        uint32_t u = nf[2 * i];
        float a = fabsf(bits2f(u << 16));
        if (a == 0.f || (a > 1e-5f && a < 100.f)) ++sane;
    }
    flag[0] = (sane >= 128) ? 0 : 1;
}

struct ParamTable {
    const void* src[14];
    int off[15];
};

__global__ void convert_params_kernel(ParamTable T, const int* __restrict__ mode,
                                      float* __restrict__ out) {
    int i = blockIdx.x * blockDim.x + threadIdx.x;
    if (i >= T.off[14]) return;
    int k = 0;
    while (k < 13 && i >= T.off[k + 1]) ++k;
    int j = i - T.off[k];
    out[i] = (*mode == 0) ? b2f(((const bf16*)T.src[k])[j]) : ((const float*)T.src[k])[j];
}

// wae[d*3+h] = sum_f We[d*96 + h*32 + f] * ae[h*32 + f]
__global__ void fold_wae_kernel(const float* __restrict__ We, const float* __restrict__ ae,
                                float* __restrict__ wae) {
    int t = threadIdx.x;
    if (t >= 96) return;
    int d = t / 3, h = t - d * 3;
    float acc = 0.f;
    for (int f = 0; f < 32; ++f) acc += We[d * 96 + h * 32 + f] * ae[h * 32 + f];
    wae[t] = acc;
}

// ---------------------------------------------------------------------------
// CSR build: histogram (records per-edge rank) -> scan -> pos.
// ---------------------------------------------------------------------------
__global__ void hist_rank_kernel(const int* __restrict__ dst, int* __restrict__ cnt,
                                 int* __restrict__ rank, int E) {
    int e = blockIdx.x * blockDim.x + threadIdx.x;
    if (e < E) rank[e] = atomicAdd(&cnt[dst[e]], 1);
}

__global__ void block_sum_kernel(const int* __restrict__ deg, int* __restrict__ bsums, int N) {
    __shared__ int sd[256];
    int t = threadIdx.x;
    int i = blockIdx.x * 256 + t;
    sd[t] = (i < N) ? deg[i] : 0;
    __syncthreads();
    for (int o = 128; o > 0; o >>= 1) {
        if (t < o) sd[t] += sd[t + o];
        __syncthreads();
    }
    if (t == 0) bsums[blockIdx.x] = sd[0];
}

__global__ void scan_bsums_kernel(int* __restrict__ bsums, int nb) {
    __shared__ int a[512], b[512];
    int t = threadIdx.x;
    int v = (t < nb) ? bsums[t] : 0;
    a[t] = v;
    __syncthreads();
    int* in = a;
    int* out = b;
    for (int o = 1; o < 512; o <<= 1) {
        out[t] = in[t] + ((t >= o) ? in[t - o] : 0);
        __syncthreads();
        int* tmp = in; in = out; out = tmp;
    }
    if (t < nb) bsums[t] = in[t] - v;
}

__global__ void scan_expand_kernel(const int* __restrict__ deg, const int* __restrict__ boffs,
                                   int* __restrict__ row_start, int N) {
    __shared__ int a[256], b[256];
    int t = threadIdx.x;
    int i = blockIdx.x * 256 + t;
    int v = (i < N) ? deg[i] : 0;
    a[t] = v;
    __syncthreads();
    int* in = a;
    int* out = b;
    for (int o = 1; o < 256; o <<= 1) {
        out[t] = in[t] + ((t >= o) ? in[t - o] : 0);
        __syncthreads();
        int* tmp = in; in = out; out = tmp;
    }
    if (i < N) row_start[i] = boffs[blockIdx.x] + in[t] - v;
}

__global__ void set_val_kernel(int* __restrict__ p, int v) { p[0] = v; }

// pos[e] = row_start[dst[e]] + rank[e]  (overwrites rank in place).
// Moves the dst->row_start dependent-load chain OUT of the heavy scatter:
// streaming reads of dst/rank, L2-resident row_start gather, streaming write.
__global__ void pos_kernel(const int* __restrict__ dst, const int* __restrict__ row_start,
                           int* __restrict__ rank_pos, int E) {
    int e = blockIdx.x * blockDim.x + threadIdx.x;
    if (e < E) rank_pos[e] = row_start[dst[e]] + rank_pos[e];
}

// ---------------------------------------------------------------------------
// Register-tiled node transform: 64 nodes/block, W staged in LDS, thread
// computes a 4-row x 6-col tile.  X tile stride DIN+1 (no bank conflicts).
// ---------------------------------------------------------------------------
template <int DIN>
__global__ void ft_elr_tiled_kernel(const void* __restrict__ X, int kind,
                                    const int* __restrict__ mode,
                                    const float* __restrict__ W,
                                    const float* __restrict__ al, const float* __restrict__ ar,
                                    float* __restrict__ ft, float* __restrict__ elr, int N) {
    __shared__ float ws[DIN * 96];
    __shared__ float xb[64 * 97];            // X tile (stride DIN+1), reused as fs (stride 97)
    const int t = threadIdx.x;
    const int base = blockIdx.x * 64;
    const int m = *mode;

    // stage W
    for (int i = t; i < DIN * 96; i += 256) ws[i] = W[i];
    // stage X (zero-pad rows past N)
    for (int i = t; i < 64 * DIN; i += 256) {
        int ln = i / DIN, d = i - ln * DIN;
        int node = base + ln;
        float v = 0.f;
        if (node < N) {
            size_t idx = (size_t)node * DIN + d;
            if (kind == 1)   v = ((const float*)X)[idx];
            else if (m == 0) v = b2f(((const bf16*)X)[idx]);
            else             v = ((const float*)X)[idx];
        }
        xb[ln * (DIN + 1) + d] = v;
    }
    __syncthreads();

    const int cx = t & 15;        // 16 col groups of 6
    const int ry = t >> 4;        // 16 row groups of 4
    const int c0 = cx * 6;
    const int r0 = ry * 4;

    float acc[4][6];
#pragma unroll
    for (int i = 0; i < 4; ++i)
#pragma unroll
        for (int j = 0; j < 6; ++j) acc[i][j] = 0.f;

#pragma unroll 4
    for (int d = 0; d < DIN; ++d) {
        float xv[4];
#pragma unroll
        for (int i = 0; i < 4; ++i) xv[i] = xb[(r0 + i) * (DIN + 1) + d];
        const float* wr = ws + d * 96 + c0;
        float wv[6];
#pragma unroll
        for (int j = 0; j < 6; ++j) wv[j] = wr[j];
#pragma unroll
        for (int i = 0; i < 4; ++i)
#pragma unroll
            for (int j = 0; j < 6; ++j) acc[i][j] += xv[i] * wv[j];
    }
    __syncthreads();   // xb reads done; safe to overwrite as fs

    // accs -> fs (stride 97)
#pragma unroll
    for (int i = 0; i < 4; ++i) {
        float* fr = xb + (r0 + i) * 97 + c0;
#pragma unroll
        for (int j = 0; j < 6; ++j) fr[j] = acc[i][j];
    }
    __syncthreads();

    // coalesced ft write
    for (int i = t; i < 64 * 96; i += 256) {
        int ln = i / 96, c = i - ln * 96;
        int node = base + ln;
        if (node < N) ft[(size_t)node * 96 + c] = xb[ln * 97 + c];
    }
    // el/er dots: 64 nodes x 6 (h x {l,r})
    for (int i = t; i < 384; i += 256) {
        int ln = i / 6, q = i - ln * 6;
        int h = q >> 1, isr = q & 1;
        int node = base + ln;
        if (node < N) {
            const float* av = (isr ? ar : al) + h * 32;
            const float* fr = xb + ln * 97 + h * 32;
            float acc2 = 0.f;
#pragma unroll
            for (int f = 0; f < 32; ++f) acc2 += fr[f] * av[f];
            elr[node * 6 + isr * 3 + h] = acc2;
        }
    }
}

// ---------------------------------------------------------------------------
// Fused scatter + both layers' edge-feature dots.  Single edge per thread
// (44 VGPR, no spill -- the proven R3 shape) with ZERO dependent loads:
// pos[e] is precomputed, so src, pos, and the 4 efeats loads all issue
// immediately; one wait; compute; two 16B random stores (SA for layer 1,
// SB for layer 2 -- split so each aggregate reads only its own 16B/edge).
// ---------------------------------------------------------------------------
__global__ void scatter_edge_kernel(const void* __restrict__ ef, const int* __restrict__ mode,
                                    const float* __restrict__ wae1, const float* __restrict__ wae2,
                                    const int* __restrict__ src,
                                    const int* __restrict__ pos,
                                    float4* __restrict__ SA, float4* __restrict__ SB, int E) {
    __shared__ float w1[96];
    __shared__ float w2[96];
    int t = threadIdx.x;
    if (t < 96) { w1[t] = wae1[t]; w2[t] = wae2[t]; }
    __syncthreads();
    int e = blockIdx.x * blockDim.x + t;
    if (e >= E) return;
    int m = *mode;
    int si = src[e];
    int p  = pos[e];

    float x[32];
    if (m == 0) {
        const uint4* pp = (const uint4*)((const uint16_t*)ef + (size_t)e * 32);
#pragma unroll
        for (int q = 0; q < 4; ++q) {
            uint4 u = pp[q];
            x[q * 8 + 0] = bits2f(u.x << 16); x[q * 8 + 1] = bits2f(u.x & 0xffff0000u);
            x[q * 8 + 2] = bits2f(u.y << 16); x[q * 8 + 3] = bits2f(u.y & 0xffff0000u);
            x[q * 8 + 4] = bits2f(u.z << 16); x[q * 8 + 5] = bits2f(u.z & 0xffff0000u);
            x[q * 8 + 6] = bits2f(u.w << 16); x[q * 8 + 7] = bits2f(u.w & 0xffff0000u);
        }
    } else {
        const float4* pp = (const float4*)((const float*)ef + (size_t)e * 32);
#pragma unroll
        for (int q = 0; q < 8; ++q) {
            float4 u = pp[q];
            x[q * 4 + 0] = u.x; x[q * 4 + 1] = u.y; x[q * 4 + 2] = u.z; x[q * 4 + 3] = u.w;
        }
    }
    float a0 = 0.f, a1 = 0.f, a2 = 0.f;   // ee1
    float c0 = 0.f, c1 = 0.f, c2 = 0.f;   // ee2
#pragma unroll
    for (int d = 0; d < 32; ++d) {
        float xv = x[d];
        a0 += xv * w1[d * 3 + 0];
        a1 += xv * w1[d * 3 + 1];
        a2 += xv * w1[d * 3 + 2];
        c0 += xv * w2[d * 3 + 0];
        c1 += xv * w2[d * 3 + 1];
        c2 += xv * w2[d * 3 + 2];
    }
    SA[p] = make_float4(__int_as_float(si), a0, a1, a2);
    SB[p] = make_float4(__int_as_float(si), c0, c1, c2);
}

// ---------------------------------------------------------------------------
// Aggregation with fused edge softmax.  S entry: {src, ee0, ee1, ee2} (16B).
// er hoisted once per node; el[sv] broadcast load co-indexed with ft[sv].
// 32 lanes per node; lane handles features lane, lane+32, lane+64.
// ---------------------------------------------------------------------------
__global__ void aggregate_kernel(const float* __restrict__ ft, const float4* __restrict__ S,
                                 const int* __restrict__ row_start,
                                 const float* __restrict__ elr,
                                 const float* __restrict__ bias,
                                 int do_relu,
                                 float* __restrict__ R, int N) {
    int t = threadIdx.x;
    int node = blockIdx.x * 8 + (t >> 5);
    int lane = t & 31;
    if (node >= N) return;
    int beg = row_start[node], end = row_start[node + 1];
    float er0 = elr[node * 6 + 3], er1 = elr[node * 6 + 4], er2 = elr[node * 6 + 5];
    float a0 = 0.f, a1 = 0.f, a2 = 0.f, s0 = 0.f, s1 = 0.f, s2 = 0.f;
    int i = beg;
    for (; i + 4 <= end; i += 4) {
#pragma unroll
        for (int u = 0; u < 4; ++u) {
            float4 q = S[i + u];
            int sv = __float_as_int(q.x);
            float2 el01 = *(const float2*)(elr + sv * 6);
            float  el2  = elr[sv * 6 + 2];
            float l0 = el01.x + er0 + q.y;
            float l1 = el01.y + er1 + q.z;
            float l2 = el2    + er2 + q.w;
            l0 = (l0 > 0.f) ? l0 : 0.2f * l0;
            l1 = (l1 > 0.f) ? l1 : 0.2f * l1;
            l2 = (l2 > 0.f) ? l2 : 0.2f * l2;
            float e0 = __expf(l0), e1 = __expf(l1), e2 = __expf(l2);
            const float* fr = ft + (size_t)sv * 96;
            a0 += fr[lane] * e0;
            a1 += fr[lane + 32] * e1;
            a2 += fr[lane + 64] * e2;
            s0 += e0; s1 += e1; s2 += e2;
        }
    }
    for (; i < end; ++i) {
        float4 q = S[i];
        int sv = __float_as_int(q.x);
        float2 el01 = *(const float2*)(elr + sv * 6);
        float  el2  = elr[sv * 6 + 2];
        float l0 = el01.x + er0 + q.y;
        float l1 = el01.y + er1 + q.z;
        float l2 = el2    + er2 + q.w;
        l0 = (l0 > 0.f) ? l0 : 0.2f * l0;
        l1 = (l1 > 0.f) ? l1 : 0.2f * l1;
        l2 = (l2 > 0.f) ? l2 : 0.2f * l2;
        float e0 = __expf(l0), e1 = __expf(l1), e2 = __expf(l2);
        const float* fr = ft + (size_t)sv * 96;
        a0 += fr[lane] * e0;
        a1 += fr[lane + 32] * e1;
        a2 += fr[lane + 64] * e2;
        s0 += e0; s1 += e1; s2 += e2;
    }
    float r0, r1, r2;
    if (end > beg) { r0 = a0 / s0; r1 = a1 / s1; r2 = a2 / s2; }
    else           { r0 = r1 = r2 = 0.f; }
    r0 += bias[lane]; r1 += bias[lane + 32]; r2 += bias[lane + 64];
    if (do_relu) { r0 = fmaxf(r0, 0.f); r1 = fmaxf(r1, 0.f); r2 = fmaxf(r2, 0.f); }
    float* out = R + (size_t)node * 96;
    out[lane] = r0; out[lane + 32] = r1; out[lane + 64] = r2;
}

// Per node (8/block): u[n,c] = h@Wp[0:96,c] + bp[c]; v[n,c] = h@Wp[96:,c]
__global__ void uv_kernel(const float* __restrict__ h, const float* __restrict__ Wp,
                          const float* __restrict__ bp, float* __restrict__ uv, int N) {
    __shared__ float hs[8 * 96];
    int base = blockIdx.x * 8;
    int t = threadIdx.x;
    for (int i = t; i < 768; i += 256) {
        int ln = i / 96, c = i - ln * 96;
        int node = base + ln;
        hs[i] = (node < N) ? h[(size_t)node * 96 + c] : 0.f;
    }
    __syncthreads();
    if (t < 160) {
        int ln = t / 20, q = t - ln * 20;
        int half = q / 10, c = q - half * 10;
        int node = base + ln;
        if (node < N) {
            float acc = half ? 0.f : bp[c];
            const float* hr = hs + ln * 96;
            const float* wcol = Wp + half * 960 + c;
            for (int j = 0; j < 96; ++j) acc += hr[j] * wcol[j * 10];
            uv[node * 20 + q] = acc;
        }
    }
}

__global__ void score_kernel(const float* __restrict__ uv, const int* __restrict__ src,
                             const int* __restrict__ dst, const int* __restrict__ mode,
                             void* __restrict__ out, int E) {
    int e = blockIdx.x * blockDim.x + threadIdx.x;
    if (e >= E) return;
    int si = src[e], di = dst[e];
    const float* u = uv + (size_t)si * 20;
    const float* v = uv + (size_t)di * 20 + 10;
    float r[10];
#pragma unroll
    for (int c = 0; c < 10; ++c) r[c] = u[c] + v[c];
    if (*mode == 0) {
        bf16 o[10];
#pragma unroll
        for (int c = 0; c < 10; ++c) o[c] = __float2bfloat16(r[c]);
        uint32_t* po = (uint32_t*)((bf16*)out + (size_t)e * 10);
        const uint32_t* ps = (const uint32_t*)o;
#pragma unroll
        for (int q = 0; q < 5; ++q) po[q] = ps[q];
    } else {
        float2* po = (float2*)((float*)out + (size_t)e * 10);
#pragma unroll
        for (int q = 0; q < 5; ++q) po[q] = make_float2(r[2 * q], r[2 * q + 1]);
    }
}

extern "C" void kernel_launch(void* const* d_in, const int* in_sizes, int n_in,
                              void* d_out, int out_size, void* d_ws, size_t ws_size,
                              hipStream_t stream) {
    const void* nfeats = d_in[0];
    const void* efeats = d_in[1];
    const int* src = (const int*)d_in[2];
    const int* dst = (const int*)d_in[3];

    const int N = in_sizes[0] / 64;
    const int E = in_sizes[2];

    // ---- workspace (~138 MB) ----
    char* w = (char*)d_ws;
    auto alloc = [&](size_t bytes) {
        void* p = (void*)w;
        w += (bytes + 255) & ~(size_t)255;
        return p;
    };
    int*    flag      = (int*)alloc(256);
    float*  pbuf      = (float*)alloc((size_t)24202 * 4);
    float*  wae1      = (float*)alloc(96 * 4);
    float*  wae2      = (float*)alloc(96 * 4);
    float*  R         = (float*)alloc((size_t)N * 96 * 4);   // h (aggregate out)
    float*  F         = (float*)alloc((size_t)N * 96 * 4);   // ft per layer
    float4* SA        = (float4*)alloc((size_t)E * 16);      // {src, ee1*3}
    float4* SB        = (float4*)alloc((size_t)E * 16);      // {src, ee2*3}
    float*  elr       = (float*)alloc((size_t)N * 6 * 4);
    int*    row_start = (int*)alloc((size_t)(N + 1) * 4);
    int*    cnt       = (int*)alloc((size_t)N * 4);
    int*    bsums     = (int*)alloc(512 * 4);
    int*    rank      = (int*)alloc((size_t)E * 4);           // becomes pos[] after pos_kernel
    float*  uv        = (float*)SA;                           // SA dead after layer 1... NO:
    // SA is read by aggregate layer 1 only; SB by layer 2.  uv is written after
    // both aggregates, so alias uv onto SA (dead by then).

    const int ns[14] = {64*96, 32*96, 96, 96, 96, 96, 96*96, 32*96, 96, 96, 96, 96, 192*10, 10};
    ParamTable T;
    int off = 0;
    for (int k = 0; k < 14; ++k) { T.src[k] = d_in[4 + k]; T.off[k] = off; off += ns[k]; }
    T.off[14] = off;
    float* W1f  = pbuf + T.off[0];
    float* We1f = pbuf + T.off[1];
    float* al1f = pbuf + T.off[2];
    float* ar1f = pbuf + T.off[3];
    float* ae1f = pbuf + T.off[4];
    float* b1f  = pbuf + T.off[5];
    float* W2f  = pbuf + T.off[6];
    float* We2f = pbuf + T.off[7];
    float* al2f = pbuf + T.off[8];
    float* ar2f = pbuf + T.off[9];
    float* ae2f = pbuf + T.off[10];
    float* b2f_ = pbuf + T.off[11];
    float* Wpf  = pbuf + T.off[12];
    float* bpf  = pbuf + T.off[13];

    dim3 b256(256);
    int eblocks    = (E + 255) / 256;
    int nodeBlocks = (N + 7) / 8;
    int tileBlocks = (N + 63) / 64;
    int nb         = (N + 255) / 256;

    hipLaunchKernelGGL(detect_mode_kernel, dim3(1), dim3(64), 0, stream,
                       (const uint16_t*)nfeats, flag);
    hipLaunchKernelGGL(convert_params_kernel, dim3((off + 255) / 256), b256, 0, stream,
                       T, flag, pbuf);
    hipLaunchKernelGGL(fold_wae_kernel, dim3(1), dim3(128), 0, stream, We1f, ae1f, wae1);
    hipLaunchKernelGGL(fold_wae_kernel, dim3(1), dim3(128), 0, stream, We2f, ae2f, wae2);

    // ---- CSR offsets + per-edge rank -> pos ----
    hipMemsetAsync(cnt, 0, (size_t)N * 4, stream);
    hipLaunchKernelGGL(hist_rank_kernel, dim3(eblocks), b256, 0, stream, dst, cnt, rank, E);
    hipLaunchKernelGGL(block_sum_kernel, dim3(nb), b256, 0, stream, cnt, bsums, N);
    hipLaunchKernelGGL(scan_bsums_kernel, dim3(1), dim3(512), 0, stream, bsums, nb);
    hipLaunchKernelGGL(scan_expand_kernel, dim3(nb), b256, 0, stream, cnt, bsums, row_start, N);
    hipLaunchKernelGGL(set_val_kernel, dim3(1), dim3(1), 0, stream, row_start + N, E);
    hipLaunchKernelGGL(pos_kernel, dim3(eblocks), b256, 0, stream, dst, row_start, rank, E);

    // ---- fused scatter + both layers' edge-feature dots (ONE efeats sweep) ----
    hipLaunchKernelGGL(scatter_edge_kernel, dim3(eblocks), b256, 0, stream,
                       efeats, flag, wae1, wae2, src, rank, SA, SB, E);

    // ---- layer 1 ----
    hipLaunchKernelGGL((ft_elr_tiled_kernel<64>), dim3(tileBlocks), b256, 0, stream,
                       nfeats, 0, flag, W1f, al1f, ar1f, F, elr, N);
    hipLaunchKernelGGL(aggregate_kernel, dim3(nodeBlocks), b256, 0, stream,
                       F, SA, row_start, elr, b1f, 1, R, N);

    // ---- layer 2 ----
    hipLaunchKernelGGL((ft_elr_tiled_kernel<96>), dim3(tileBlocks), b256, 0, stream,
                       (const void*)R, 1, flag, W2f, al2f, ar2f, F, elr, N);
    hipLaunchKernelGGL(aggregate_kernel, dim3(nodeBlocks), b256, 0, stream,
                       F, SB, row_start, elr, b2f_, 0, R, N);

    // ---- predictor ----
    hipLaunchKernelGGL(uv_kernel, dim3(nodeBlocks), b256, 0, stream, R, Wpf, bpf, uv, N);
    hipLaunchKernelGGL(score_kernel, dim3(eblocks), b256, 0, stream,
                       uv, src, dst, flag, d_out, E);
}